// Round 2
// baseline (177.887 us; speedup 1.0000x reference)
//
#include <hip/hip_runtime.h>
#include <cstdint>
#include <cstddef>

#define E_TOT 2048
#define A_TOT 512
#define FEAT  128
#define N_UP  1024
#define K_RBF 32
#define DIM   256

// ---------------------------------------------------------------------------
// Main pass (rbf fused): each block owns a (EB e x AB a) tile, reads its h
// slice once, produces atom partials (sum over tile electrons, register acc)
// and elec partials (sum over tile atoms, batched LDS reduce every 8 e).
// Threads: r = t>>5 in [0,8) indexes atoms within a group, f4 = t&31 is the
// float4 index into FEAT=128.
// ---------------------------------------------------------------------------
template <int EB, int AB>
__global__ __launch_bounds__(256, 4) void main_pass(
    const float* __restrict__ h, const float* __restrict__ r_im,
    const float* __restrict__ mu, const float* __restrict__ sigma,
    float* __restrict__ ws_atom,   // [E_TOT/EB][A_TOT][FEAT]
    float* __restrict__ ws_elec) { // [A_TOT/AB][E_TOT][FEAT]
  constexpr int GA = A_TOT / AB;
  constexpr int NIA = AB / 8;
  static_assert(EB % 8 == 0, "EB multiple of 8");
  const int bid = blockIdx.x;
  const int g_a = bid % GA;
  const int g_e = bid / GA;
  const int e0 = g_e * EB, a0 = g_a * AB;
  const int t = threadIdx.x;
  const int r = t >> 5, f4 = t & 31;

  __shared__ float s_mu[K_RBF], s_inv[K_RBF];
  __shared__ float rbf_lds[EB * AB];
  __shared__ float4 esum_lds[8 * 256];  // [e_l in batch][r][f4], 32 KB

  if (t < K_RBF) {
    s_mu[t] = mu[t];
    float s = sigma[t];
    float sp = (s > 20.0f) ? s : log1pf(__expf(s));  // softplus
    s_inv[t] = 1.0f / sp;
  }
  __syncthreads();

  // rbf for this tile (each (e,a) belongs to exactly one block -> no redundancy)
  for (int i = t; i < EB * AB; i += 256) {
    int e_l = i / AB, a_l = i % AB;
    float rv = r_im[(size_t)(e0 + e_l) * A_TOT + a0 + a_l];
    float acc = 0.0f;
#pragma unroll
    for (int k = 0; k < K_RBF; ++k) {
      float d = rv - s_mu[k];
      acc += __expf(-d * d * s_inv[k]);
    }
    rbf_lds[i] = acc * (1.0f / K_RBF);
  }
  __syncthreads();

  float4 atom_acc[NIA];
#pragma unroll
  for (int i = 0; i < NIA; ++i) atom_acc[i] = make_float4(0.f, 0.f, 0.f, 0.f);

  for (int eb = 0; eb < EB; eb += 8) {
#pragma unroll
    for (int e_l = 0; e_l < 8; ++e_l) {
      const int e = eb + e_l;
      const float* hrow = h + ((size_t)(e0 + e) * A_TOT + a0) * FEAT;
      float4 esum = make_float4(0.f, 0.f, 0.f, 0.f);
#pragma unroll
      for (int ia = 0; ia < NIA; ++ia) {
        const int a_l = ia * 8 + r;
        float4 hv = *reinterpret_cast<const float4*>(hrow + a_l * FEAT + f4 * 4);
        float rb = rbf_lds[e * AB + a_l];
        float4 v = make_float4(hv.x * rb, hv.y * rb, hv.z * rb, hv.w * rb);
        atom_acc[ia].x += v.x; atom_acc[ia].y += v.y;
        atom_acc[ia].z += v.z; atom_acc[ia].w += v.w;
        esum.x += v.x; esum.y += v.y; esum.z += v.z; esum.w += v.w;
      }
      esum_lds[e_l * 256 + t] = esum;  // exclusive slot, no barrier needed
    }
    __syncthreads();
    // cooperative reduce over r: thread t handles (e_l = t>>5, f4 = t&31)
    {
      const int e_l = t >> 5;
      float4 s = make_float4(0.f, 0.f, 0.f, 0.f);
#pragma unroll
      for (int rr = 0; rr < 8; ++rr) {
        float4 v = esum_lds[e_l * 256 + rr * 32 + f4];
        s.x += v.x; s.y += v.y; s.z += v.z; s.w += v.w;
      }
      reinterpret_cast<float4*>(ws_elec)
          [((size_t)g_a * E_TOT + e0 + eb + e_l) * 32 + f4] = s;
    }
    __syncthreads();
  }

#pragma unroll
  for (int ia = 0; ia < NIA; ++ia) {
    const int a_l = ia * 8 + r;
    reinterpret_cast<float4*>(ws_atom)
        [((size_t)g_e * A_TOT + a0 + a_l) * 32 + f4] = atom_acc[ia];
  }
}

// ---------------------------------------------------------------------------
// Merged epilogue. Blocks [0, A_TOT): one block per atom -> spin means, 256-dot,
// tanh*gain. Blocks [A_TOT, A_TOT+256): elec partial reduce -> out tail.
// ---------------------------------------------------------------------------
__global__ __launch_bounds__(256) void finals(
    const float* __restrict__ ws_atom, const float* __restrict__ ws_elec,
    const float* __restrict__ W, const float* __restrict__ bias,
    float* __restrict__ out, int ge_total, int ga_total) {
  const int t = threadIdx.x;
  if (blockIdx.x < A_TOT) {
    const int a = blockIdx.x;
    __shared__ float s_in[2 * FEAT];
    const int spin = t >> 7;
    const int f = t & 127;
    const int gh = ge_total >> 1;
    const int g0 = spin * gh;
    float acc = 0.0f;
#pragma unroll 4
    for (int g = 0; g < gh; ++g) {
      acc += ws_atom[((size_t)(g0 + g) * A_TOT + a) * FEAT + f];
    }
    s_in[t] = acc * (1.0f / (float)N_UP);
    __syncthreads();
    float o = bias[t];
#pragma unroll 4
    for (int k = 0; k < 2 * FEAT; ++k) {
      o += s_in[k] * W[(size_t)k * DIM + t];
    }
    out[(size_t)a * DIM + t] = tanhf(o) * (5.0f / 3.0f);
  } else {
    const int idx = (int)(blockIdx.x - A_TOT) * 256 + t;  // float4 index
    const int n4 = E_TOT * FEAT / 4;
    const float4* in4 = reinterpret_cast<const float4*>(ws_elec);
    float4 s = make_float4(0.f, 0.f, 0.f, 0.f);
    for (int g = 0; g < ga_total; ++g) {
      float4 v = in4[(size_t)g * n4 + idx];
      s.x += v.x; s.y += v.y; s.z += v.z; s.w += v.w;
    }
    const float inv = 1.0f / (float)A_TOT;
    reinterpret_cast<float4*>(out + (size_t)A_TOT * DIM)[idx] =
        make_float4(s.x * inv, s.y * inv, s.z * inv, s.w * inv);
  }
}

// ---------------------------------------------------------------------------
extern "C" void kernel_launch(void* const* d_in, const int* in_sizes, int n_in,
                              void* d_out, int out_size, void* d_ws, size_t ws_size,
                              hipStream_t stream) {
  const float* h     = (const float*)d_in[0];  // (2048,512,128)
  const float* r_im  = (const float*)d_in[1];  // (2048,512)
  const float* mu    = (const float*)d_in[2];  // (32,)
  const float* sigma = (const float*)d_in[3];  // (32,)
  const float* W     = (const float*)d_in[4];  // (256,256)
  const float* b     = (const float*)d_in[5];  // (256,)
  float* out = (float*)d_out;

  const size_t fE = (size_t)8 * E_TOT * FEAT;  // GA = 8 (AB = 64)
  auto fA = [](int EB) { return (size_t)(E_TOT / EB) * A_TOT * FEAT; };

  float* ws_atom = (float*)d_ws;
  const int finals_grid = A_TOT + (E_TOT * FEAT / 4) / 256;  // 512 + 256

  if (ws_size >= (fA(16) + fE) * 4) {            // ~42 MB
    constexpr int GE = E_TOT / 16, GA = A_TOT / 64;  // 128, 8
    float* ws_elec = ws_atom + (size_t)GE * A_TOT * FEAT;
    main_pass<16, 64><<<GE * GA, 256, 0, stream>>>(h, r_im, mu, sigma, ws_atom, ws_elec);
    finals<<<finals_grid, 256, 0, stream>>>(ws_atom, ws_elec, W, b, out, GE, GA);
  } else if (ws_size >= (fA(32) + fE) * 4) {     // ~25 MB
    constexpr int GE = E_TOT / 32, GA = A_TOT / 64;  // 64, 8
    float* ws_elec = ws_atom + (size_t)GE * A_TOT * FEAT;
    main_pass<32, 64><<<GE * GA, 256, 0, stream>>>(h, r_im, mu, sigma, ws_atom, ws_elec);
    finals<<<finals_grid, 256, 0, stream>>>(ws_atom, ws_elec, W, b, out, GE, GA);
  } else {                                       // ~17 MB
    constexpr int GE = E_TOT / 64, GA = A_TOT / 64;  // 32, 8
    float* ws_elec = ws_atom + (size_t)GE * A_TOT * FEAT;
    main_pass<64, 64><<<GE * GA, 256, 0, stream>>>(h, r_im, mu, sigma, ws_atom, ws_elec);
    finals<<<finals_grid, 256, 0, stream>>>(ws_atom, ws_elec, W, b, out, GE, GA);
  }
}

// Round 3
// 153.186 us; speedup vs baseline: 1.1612x; 1.1612x over previous
//
#include <hip/hip_runtime.h>
#include <cstdint>
#include <cstddef>

#define E_TOT 2048
#define A_TOT 512
#define FEAT  128
#define N_UP  1024
#define K_RBF 32
#define DIM   256

// ---------------------------------------------------------------------------
// Main pass (rbf fused): each block owns a (EB e x AB a) tile, reads its h
// slice once, produces atom partials (register acc over tile electrons) and
// elec partials (sum over tile atoms, batched LDS reduce every 8 electrons).
// Threads: r = t>>5 in [0,8) indexes atoms within an 8-group, f4 = t&31 is
// the float4 index into FEAT=128.
// ---------------------------------------------------------------------------
template <int EB, int AB>
__global__ __launch_bounds__(256) void main_pass(
    const float* __restrict__ h, const float* __restrict__ r_im,
    const float* __restrict__ mu, const float* __restrict__ sigma,
    float* __restrict__ ws_atom,   // [E_TOT/EB][A_TOT][FEAT]
    float* __restrict__ ws_elec) { // [A_TOT/AB][E_TOT][FEAT]
  constexpr int GA = A_TOT / AB;
  constexpr int NIA = AB / 8;
  static_assert(EB % 8 == 0, "EB multiple of 8");
  const int bid = blockIdx.x;
  const int g_a = bid % GA;
  const int g_e = bid / GA;
  const int e0 = g_e * EB, a0 = g_a * AB;
  const int t = threadIdx.x;
  const int r = t >> 5, f4 = t & 31;

  __shared__ float s_mu[K_RBF], s_inv[K_RBF];
  __shared__ float rbf_lds[EB * AB];
  __shared__ float4 esum_lds[8 * 256];  // [e_l in batch][r][f4], 32 KB

  if (t < K_RBF) {
    s_mu[t] = mu[t];
    float s = sigma[t];
    float sp = (s > 20.0f) ? s : log1pf(__expf(s));  // softplus
    s_inv[t] = 1.0f / sp;
  }
  __syncthreads();

  // rbf for this tile (each (e,a) belongs to exactly one block -> no redundancy)
  for (int i = t; i < EB * AB; i += 256) {
    int e_l = i / AB, a_l = i % AB;
    float rv = r_im[(size_t)(e0 + e_l) * A_TOT + a0 + a_l];
    float acc = 0.0f;
#pragma unroll
    for (int k = 0; k < K_RBF; ++k) {
      float d = rv - s_mu[k];
      acc += __expf(-d * d * s_inv[k]);
    }
    rbf_lds[i] = acc * (1.0f / K_RBF);
  }
  __syncthreads();

  float4 atom_acc[NIA];
#pragma unroll
  for (int i = 0; i < NIA; ++i) atom_acc[i] = make_float4(0.f, 0.f, 0.f, 0.f);

  for (int eb = 0; eb < EB; eb += 8) {
#pragma unroll
    for (int e_l = 0; e_l < 8; ++e_l) {
      const int e = eb + e_l;
      const float* hrow = h + ((size_t)(e0 + e) * A_TOT + a0) * FEAT;
      float4 esum = make_float4(0.f, 0.f, 0.f, 0.f);
#pragma unroll
      for (int ia = 0; ia < NIA; ++ia) {
        const int a_l = ia * 8 + r;
        float4 hv = *reinterpret_cast<const float4*>(hrow + a_l * FEAT + f4 * 4);
        float rb = rbf_lds[e * AB + a_l];
        float4 v = make_float4(hv.x * rb, hv.y * rb, hv.z * rb, hv.w * rb);
        atom_acc[ia].x += v.x; atom_acc[ia].y += v.y;
        atom_acc[ia].z += v.z; atom_acc[ia].w += v.w;
        esum.x += v.x; esum.y += v.y; esum.z += v.z; esum.w += v.w;
      }
      esum_lds[e_l * 256 + t] = esum;  // exclusive slot, no barrier in batch
    }
    __syncthreads();
    // cooperative reduce over r: thread t handles (e_l = t>>5, f4 = t&31)
    {
      const int e_l = t >> 5;
      float4 s = make_float4(0.f, 0.f, 0.f, 0.f);
#pragma unroll
      for (int rr = 0; rr < 8; ++rr) {
        float4 v = esum_lds[e_l * 256 + rr * 32 + f4];
        s.x += v.x; s.y += v.y; s.z += v.z; s.w += v.w;
      }
      reinterpret_cast<float4*>(ws_elec)
          [((size_t)g_a * E_TOT + e0 + eb + e_l) * 32 + f4] = s;
    }
    __syncthreads();
  }

#pragma unroll
  for (int ia = 0; ia < NIA; ++ia) {
    const int a_l = ia * 8 + r;
    reinterpret_cast<float4*>(ws_atom)
        [((size_t)g_e * A_TOT + a0 + a_l) * 32 + f4] = atom_acc[ia];
  }
}

// ---------------------------------------------------------------------------
// Merged epilogue. Blocks [0, A_TOT): one block per atom -> spin means, 256-dot,
// tanh*gain. Blocks [A_TOT, A_TOT+256): elec partial reduce -> out tail.
// ---------------------------------------------------------------------------
__global__ __launch_bounds__(256) void finals(
    const float* __restrict__ ws_atom, const float* __restrict__ ws_elec,
    const float* __restrict__ W, const float* __restrict__ bias,
    float* __restrict__ out, int ge_total, int ga_total) {
  const int t = threadIdx.x;
  if (blockIdx.x < A_TOT) {
    const int a = blockIdx.x;
    __shared__ float s_in[2 * FEAT];
    const int spin = t >> 7;
    const int f = t & 127;
    const int gh = ge_total >> 1;
    const int g0 = spin * gh;
    float acc = 0.0f;
#pragma unroll 4
    for (int g = 0; g < gh; ++g) {
      acc += ws_atom[((size_t)(g0 + g) * A_TOT + a) * FEAT + f];
    }
    s_in[t] = acc * (1.0f / (float)N_UP);
    __syncthreads();
    float o = bias[t];
#pragma unroll 4
    for (int k = 0; k < 2 * FEAT; ++k) {
      o += s_in[k] * W[(size_t)k * DIM + t];
    }
    out[(size_t)a * DIM + t] = tanhf(o) * (5.0f / 3.0f);
  } else {
    const int idx = (int)(blockIdx.x - A_TOT) * 256 + t;  // float4 index
    const int n4 = E_TOT * FEAT / 4;
    const float4* in4 = reinterpret_cast<const float4*>(ws_elec);
    float4 s = make_float4(0.f, 0.f, 0.f, 0.f);
    for (int g = 0; g < ga_total; ++g) {
      float4 v = in4[(size_t)g * n4 + idx];
      s.x += v.x; s.y += v.y; s.z += v.z; s.w += v.w;
    }
    const float inv = 1.0f / (float)A_TOT;
    reinterpret_cast<float4*>(out + (size_t)A_TOT * DIM)[idx] =
        make_float4(s.x * inv, s.y * inv, s.z * inv, s.w * inv);
  }
}

// ---------------------------------------------------------------------------
extern "C" void kernel_launch(void* const* d_in, const int* in_sizes, int n_in,
                              void* d_out, int out_size, void* d_ws, size_t ws_size,
                              hipStream_t stream) {
  const float* h     = (const float*)d_in[0];  // (2048,512,128)
  const float* r_im  = (const float*)d_in[1];  // (2048,512)
  const float* mu    = (const float*)d_in[2];  // (32,)
  const float* sigma = (const float*)d_in[3];  // (32,)
  const float* W     = (const float*)d_in[4];  // (256,256)
  const float* b     = (const float*)d_in[5];  // (256,)
  float* out = (float*)d_out;

  float* ws_atom = (float*)d_ws;
  const int finals_grid = A_TOT + (E_TOT * FEAT / 4) / 256;  // 512 + 256

  // preferred: EB=32, AB=32 -> grid 1024 (4 blocks/CU), ws = 33.5 MB
  const size_t needA = ((size_t)(E_TOT / 32) * A_TOT * FEAT +
                        (size_t)(A_TOT / 32) * E_TOT * FEAT) * 4;
  // fallback: EB=64, AB=64 -> grid 256, ws = 16.8 MB
  if (ws_size >= needA) {
    constexpr int GE = E_TOT / 32, GA = A_TOT / 32;  // 64, 16
    float* ws_elec = ws_atom + (size_t)GE * A_TOT * FEAT;
    main_pass<32, 32><<<GE * GA, 256, 0, stream>>>(h, r_im, mu, sigma, ws_atom, ws_elec);
    finals<<<finals_grid, 256, 0, stream>>>(ws_atom, ws_elec, W, b, out, GE, GA);
  } else {
    constexpr int GE = E_TOT / 64, GA = A_TOT / 64;  // 32, 8
    float* ws_elec = ws_atom + (size_t)GE * A_TOT * FEAT;
    main_pass<64, 64><<<GE * GA, 256, 0, stream>>>(h, r_im, mu, sigma, ws_atom, ws_elec);
    finals<<<finals_grid, 256, 0, stream>>>(ws_atom, ws_elec, W, b, out, GE, GA);
  }
}

// Round 5
// 138.848 us; speedup vs baseline: 1.2812x; 1.1033x over previous
//
#include <hip/hip_runtime.h>
#include <cstdint>
#include <cstddef>

#define E_TOT 2048
#define A_TOT 512
#define FEAT  128
#define N_UP  1024
#define K_RBF 32
#define DIM   256

typedef float vfloat4 __attribute__((ext_vector_type(4)));

// ---------------------------------------------------------------------------
// Main pass, barrier-free hot loop. Block owns (EB e x AB a). Wave w owns
// WA=AB/4 atoms; lane: f4 = lane&31 (float4 idx in FEAT), r_lo = lane>>5.
// Per e: NIA=AB/8 vfloat4 loads/lane (wave covers its WA atoms, 1KB/inst,
// contiguous). elec-partial reduced intra-wave via shfl_down(32); each wave
// writes its own ws_elec slice (GA*4 slices total). atom-partial stays in
// registers for the whole e-loop. The only __syncthreads is after rbf staging.
// ---------------------------------------------------------------------------
template <int EB, int AB>
__global__ __launch_bounds__(256) void main_pass(
    const float* __restrict__ h, const float* __restrict__ r_im,
    const float* __restrict__ mu, const float* __restrict__ sigma,
    float* __restrict__ ws_atom,   // [E_TOT/EB][A_TOT][FEAT]
    float* __restrict__ ws_elec) { // [GA*4][E_TOT][FEAT]
  constexpr int GA = A_TOT / AB;
  constexpr int WA = AB / 4;   // atoms per wave
  constexpr int NIA = AB / 8;  // 2 atoms per ia step
  static_assert(EB % 2 == 0, "EB even");
  const int bid = blockIdx.x;
  const int g_a = bid % GA, g_e = bid / GA;
  const int e0 = g_e * EB, a0 = g_a * AB;
  const int t = threadIdx.x;
  const int wave = t >> 6, lane = t & 63;
  const int f4 = lane & 31, r_lo = lane >> 5;

  __shared__ float s_mu[K_RBF], s_inv[K_RBF];
  __shared__ float rbf_lds[EB * AB];

  if (t < K_RBF) {
    s_mu[t] = mu[t];
    float s = sigma[t];
    float sp = (s > 20.0f) ? s : log1pf(__expf(s));  // softplus
    s_inv[t] = 1.0f / sp;
  }
  __syncthreads();

  for (int i = t; i < EB * AB; i += 256) {
    int e_l = i / AB, a_l = i % AB;
    float rv = r_im[(size_t)(e0 + e_l) * A_TOT + a0 + a_l];
    float acc = 0.0f;
#pragma unroll
    for (int k = 0; k < K_RBF; ++k) {
      float d = rv - s_mu[k];
      acc += __expf(-d * d * s_inv[k]);
    }
    rbf_lds[i] = acc * (1.0f / K_RBF);
  }
  __syncthreads();  // last barrier in the kernel

  vfloat4 acc[NIA];
#pragma unroll
  for (int i = 0; i < NIA; ++i) acc[i] = (vfloat4)(0.f);

  const float* hbase = h + ((size_t)e0 * A_TOT + a0) * FEAT;
  const int col = wave * WA + r_lo;  // atom offset for ia=0

  auto ldrow = [&](vfloat4* buf, int e) {
#pragma unroll
    for (int ia = 0; ia < NIA; ++ia) {
      const float* p = hbase + (size_t)e * (A_TOT * FEAT) +
                       (col + ia * 2) * FEAT + f4 * 4;
      buf[ia] = __builtin_nontemporal_load(reinterpret_cast<const vfloat4*>(p));
    }
  };
  vfloat4* ws_e4 = reinterpret_cast<vfloat4*>(ws_elec);
  auto process = [&](const vfloat4* buf, int e) {
    vfloat4 esum = (vfloat4)(0.f);
#pragma unroll
    for (int ia = 0; ia < NIA; ++ia) {
      float rb = rbf_lds[e * AB + col + ia * 2];
      vfloat4 v = buf[ia] * rb;
      acc[ia] += v;
      esum += v;
    }
    esum.x += __shfl_down(esum.x, 32, 64);
    esum.y += __shfl_down(esum.y, 32, 64);
    esum.z += __shfl_down(esum.z, 32, 64);
    esum.w += __shfl_down(esum.w, 32, 64);
    if (lane < 32) {
      ws_e4[((size_t)(g_a * 4 + wave) * E_TOT + e0 + e) * 32 + f4] = esum;
    }
  };

  vfloat4 b0[NIA], b1[NIA];
  ldrow(b0, 0);
#pragma unroll 4
  for (int e = 0; e < EB; e += 2) {
    ldrow(b1, e + 1);
    process(b0, e);
    if (e + 2 < EB) ldrow(b0, e + 2);
    process(b1, e + 1);
  }

  vfloat4* ws_a4 = reinterpret_cast<vfloat4*>(ws_atom);
#pragma unroll
  for (int ia = 0; ia < NIA; ++ia) {
    const int a_l = col + ia * 2;
    ws_a4[((size_t)g_e * A_TOT + a0 + a_l) * 32 + f4] = acc[ia];
  }
}

// ---------------------------------------------------------------------------
// Merged epilogue. Blocks [0, A_TOT): one block per atom -> spin means,
// 256-dot, tanh*gain. Blocks [A_TOT, A_TOT+256): elec slice reduce.
// ---------------------------------------------------------------------------
__global__ __launch_bounds__(256) void finals(
    const float* __restrict__ ws_atom, const float* __restrict__ ws_elec,
    const float* __restrict__ W, const float* __restrict__ bias,
    float* __restrict__ out, int ge_total, int slices) {
  const int t = threadIdx.x;
  if (blockIdx.x < A_TOT) {
    const int a = blockIdx.x;
    __shared__ float s_in[2 * FEAT];
    const int spin = t >> 7;
    const int f = t & 127;
    const int gh = ge_total >> 1;
    const int g0 = spin * gh;
    float acc = 0.0f;
#pragma unroll 4
    for (int g = 0; g < gh; ++g) {
      acc += ws_atom[((size_t)(g0 + g) * A_TOT + a) * FEAT + f];
    }
    s_in[t] = acc * (1.0f / (float)N_UP);
    __syncthreads();
    float o = bias[t];
#pragma unroll 4
    for (int k = 0; k < 2 * FEAT; ++k) {
      o += s_in[k] * W[(size_t)k * DIM + t];
    }
    out[(size_t)a * DIM + t] = tanhf(o) * (5.0f / 3.0f);
  } else {
    const int idx = (int)(blockIdx.x - A_TOT) * 256 + t;  // vfloat4 index
    const int n4 = E_TOT * FEAT / 4;
    const vfloat4* in4 = reinterpret_cast<const vfloat4*>(ws_elec);
    vfloat4 s = (vfloat4)(0.f);
    for (int g = 0; g < slices; ++g) {
      s += in4[(size_t)g * n4 + idx];
    }
    s *= (1.0f / (float)A_TOT);
    reinterpret_cast<vfloat4*>(out + (size_t)A_TOT * DIM)[idx] = s;
  }
}

// ---------------------------------------------------------------------------
extern "C" void kernel_launch(void* const* d_in, const int* in_sizes, int n_in,
                              void* d_out, int out_size, void* d_ws, size_t ws_size,
                              hipStream_t stream) {
  const float* h     = (const float*)d_in[0];  // (2048,512,128)
  const float* r_im  = (const float*)d_in[1];  // (2048,512)
  const float* mu    = (const float*)d_in[2];  // (32,)
  const float* sigma = (const float*)d_in[3];  // (32,)
  const float* W     = (const float*)d_in[4];  // (256,256)
  const float* b     = (const float*)d_in[5];  // (256,)
  float* out = (float*)d_out;

  float* ws_atom = (float*)d_ws;
  const int finals_grid = A_TOT + (E_TOT * FEAT / 4) / 256;  // 512 + 256

  // preferred: EB=32, AB=32 -> grid 1024, slices = 64, ws = 84 MB
  const size_t needA = ((size_t)(E_TOT / 32) * A_TOT * FEAT +
                        (size_t)(A_TOT / 32) * 4 * E_TOT * FEAT) * 4;
  if (ws_size >= needA) {
    constexpr int GE = E_TOT / 32, GA = A_TOT / 32;  // 64, 16
    float* ws_elec = ws_atom + (size_t)GE * A_TOT * FEAT;
    main_pass<32, 32><<<GE * GA, 256, 0, stream>>>(h, r_im, mu, sigma, ws_atom, ws_elec);
    finals<<<finals_grid, 256, 0, stream>>>(ws_atom, ws_elec, W, b, out, GE, GA * 4);
  } else {
    // fallback: EB=64, AB=64 -> grid 256, slices = 32, ws = 42 MB
    constexpr int GE = E_TOT / 64, GA = A_TOT / 64;  // 32, 8
    float* ws_elec = ws_atom + (size_t)GE * A_TOT * FEAT;
    main_pass<64, 64><<<GE * GA, 256, 0, stream>>>(h, r_im, mu, sigma, ws_atom, ws_elec);
    finals<<<finals_grid, 256, 0, stream>>>(ws_atom, ws_elec, W, b, out, GE, GA * 4);
  }
}

// Round 6
// 136.520 us; speedup vs baseline: 1.3030x; 1.0171x over previous
//
#include <hip/hip_runtime.h>
#include <cstdint>
#include <cstddef>

#define E_TOT 2048
#define A_TOT 512
#define FEAT  128
#define N_UP  1024
#define K_RBF 32
#define DIM   256

typedef float vfloat4 __attribute__((ext_vector_type(4)));

// ---------------------------------------------------------------------------
// Main pass, barrier-free hot loop. Block owns (EB e x AB a). Wave w owns
// WA=AB/4 atoms; lane: f4 = lane&31 (float4 idx in FEAT), r_lo = lane>>5.
// Per e: NIA=AB/8 vfloat4 nontemporal loads/lane. elec-partial: intra-wave
// shfl_down(32), then LDS atomicAdd combine across the 4 waves (no barrier
// needed). Block-end: one barrier, cooperative write of the combined
// [EB][FEAT] elec slice (slices = GA, not GA*4). atom-partial stays in
// registers for the whole e-loop.
// ---------------------------------------------------------------------------
template <int EB, int AB>
__global__ __launch_bounds__(256) void main_pass(
    const float* __restrict__ h, const float* __restrict__ r_im,
    const float* __restrict__ mu, const float* __restrict__ sigma,
    float* __restrict__ ws_atom,   // [E_TOT/EB][A_TOT][FEAT]
    float* __restrict__ ws_elec) { // [GA][E_TOT][FEAT]
  constexpr int GA = A_TOT / AB;
  constexpr int WA = AB / 4;   // atoms per wave
  constexpr int NIA = AB / 8;  // 2 atoms per ia step
  static_assert(EB % 2 == 0, "EB even");
  const int bid = blockIdx.x;
  const int g_a = bid % GA, g_e = bid / GA;
  const int e0 = g_e * EB, a0 = g_a * AB;
  const int t = threadIdx.x;
  const int wave = t >> 6, lane = t & 63;
  const int f4 = lane & 31, r_lo = lane >> 5;

  __shared__ float s_mu[K_RBF], s_inv[K_RBF];
  __shared__ float rbf_lds[EB * AB];
  __shared__ float esum_lds[EB * FEAT];  // combined elec partial, 16 KB @EB=32

  if (t < K_RBF) {
    s_mu[t] = mu[t];
    float s = sigma[t];
    float sp = (s > 20.0f) ? s : log1pf(__expf(s));  // softplus
    s_inv[t] = 1.0f / sp;
  }
  __syncthreads();

  for (int i = t; i < EB * FEAT; i += 256) esum_lds[i] = 0.0f;
  for (int i = t; i < EB * AB; i += 256) {
    int e_l = i / AB, a_l = i % AB;
    float rv = r_im[(size_t)(e0 + e_l) * A_TOT + a0 + a_l];
    float acc = 0.0f;
#pragma unroll
    for (int k = 0; k < K_RBF; ++k) {
      float d = rv - s_mu[k];
      acc += __expf(-d * d * s_inv[k]);
    }
    rbf_lds[i] = acc * (1.0f / K_RBF);
  }
  __syncthreads();  // hot loop below is barrier-free

  vfloat4 acc[NIA];
#pragma unroll
  for (int i = 0; i < NIA; ++i) acc[i] = (vfloat4)(0.f);

  const float* hbase = h + ((size_t)e0 * A_TOT + a0) * FEAT;
  const int col = wave * WA + r_lo;  // atom offset for ia=0

  auto ldrow = [&](vfloat4* buf, int e) {
#pragma unroll
    for (int ia = 0; ia < NIA; ++ia) {
      const float* p = hbase + (size_t)e * (A_TOT * FEAT) +
                       (col + ia * 2) * FEAT + f4 * 4;
      buf[ia] = __builtin_nontemporal_load(reinterpret_cast<const vfloat4*>(p));
    }
  };
  auto process = [&](const vfloat4* buf, int e) {
    vfloat4 esum = (vfloat4)(0.f);
#pragma unroll
    for (int ia = 0; ia < NIA; ++ia) {
      float rb = rbf_lds[e * AB + col + ia * 2];
      vfloat4 v = buf[ia] * rb;
      acc[ia] += v;
      esum += v;
    }
    esum.x += __shfl_down(esum.x, 32, 64);
    esum.y += __shfl_down(esum.y, 32, 64);
    esum.z += __shfl_down(esum.z, 32, 64);
    esum.w += __shfl_down(esum.w, 32, 64);
    if (lane < 32) {
      float* p = &esum_lds[e * FEAT + f4 * 4];
      atomicAdd(p + 0, esum.x);
      atomicAdd(p + 1, esum.y);
      atomicAdd(p + 2, esum.z);
      atomicAdd(p + 3, esum.w);
    }
  };

  vfloat4 b0[NIA], b1[NIA];
  ldrow(b0, 0);
#pragma unroll 4
  for (int e = 0; e < EB; e += 2) {
    ldrow(b1, e + 1);
    process(b0, e);
    if (e + 2 < EB) ldrow(b0, e + 2);
    process(b1, e + 1);
  }

  // atom partials (no cross-wave dependence)
  vfloat4* ws_a4 = reinterpret_cast<vfloat4*>(ws_atom);
#pragma unroll
  for (int ia = 0; ia < NIA; ++ia) {
    const int a_l = col + ia * 2;
    ws_a4[((size_t)g_e * A_TOT + a0 + a_l) * 32 + f4] = acc[ia];
  }

  // combined elec slice write
  __syncthreads();
  vfloat4* ws_e4 = reinterpret_cast<vfloat4*>(ws_elec);
  const vfloat4* es4 = reinterpret_cast<const vfloat4*>(esum_lds);
#pragma unroll
  for (int i = t; i < EB * 32; i += 256) {
    const int e_l = i >> 5, ff = i & 31;
    ws_e4[((size_t)g_a * E_TOT + e0 + e_l) * 32 + ff] = es4[e_l * 32 + ff];
  }
}

// ---------------------------------------------------------------------------
// Merged epilogue. Blocks [0, A_TOT): one block per atom -> spin means,
// 256-dot, tanh*gain. Blocks [A_TOT, A_TOT+256): elec slice reduce.
// ---------------------------------------------------------------------------
__global__ __launch_bounds__(256) void finals(
    const float* __restrict__ ws_atom, const float* __restrict__ ws_elec,
    const float* __restrict__ W, const float* __restrict__ bias,
    float* __restrict__ out, int ge_total, int slices) {
  const int t = threadIdx.x;
  if (blockIdx.x < A_TOT) {
    const int a = blockIdx.x;
    __shared__ float s_in[2 * FEAT];
    const int spin = t >> 7;
    const int f = t & 127;
    const int gh = ge_total >> 1;
    const int g0 = spin * gh;
    float acc = 0.0f;
#pragma unroll 4
    for (int g = 0; g < gh; ++g) {
      acc += ws_atom[((size_t)(g0 + g) * A_TOT + a) * FEAT + f];
    }
    s_in[t] = acc * (1.0f / (float)N_UP);
    __syncthreads();
    float o = bias[t];
#pragma unroll 4
    for (int k = 0; k < 2 * FEAT; ++k) {
      o += s_in[k] * W[(size_t)k * DIM + t];
    }
    out[(size_t)a * DIM + t] = tanhf(o) * (5.0f / 3.0f);
  } else {
    const int idx = (int)(blockIdx.x - A_TOT) * 256 + t;  // vfloat4 index
    const int n4 = E_TOT * FEAT / 4;
    const vfloat4* in4 = reinterpret_cast<const vfloat4*>(ws_elec);
    vfloat4 s = (vfloat4)(0.f);
    for (int g = 0; g < slices; ++g) {
      s += in4[(size_t)g * n4 + idx];
    }
    s *= (1.0f / (float)A_TOT);
    reinterpret_cast<vfloat4*>(out + (size_t)A_TOT * DIM)[idx] = s;
  }
}

// ---------------------------------------------------------------------------
extern "C" void kernel_launch(void* const* d_in, const int* in_sizes, int n_in,
                              void* d_out, int out_size, void* d_ws, size_t ws_size,
                              hipStream_t stream) {
  const float* h     = (const float*)d_in[0];  // (2048,512,128)
  const float* r_im  = (const float*)d_in[1];  // (2048,512)
  const float* mu    = (const float*)d_in[2];  // (32,)
  const float* sigma = (const float*)d_in[3];  // (32,)
  const float* W     = (const float*)d_in[4];  // (256,256)
  const float* b     = (const float*)d_in[5];  // (256,)
  float* out = (float*)d_out;

  float* ws_atom = (float*)d_ws;
  const int finals_grid = A_TOT + (E_TOT * FEAT / 4) / 256;  // 512 + 256

  // preferred: EB=32, AB=32 -> grid 1024, slices = 16, ws = 33.5 MB
  const size_t needA = ((size_t)(E_TOT / 32) * A_TOT * FEAT +
                        (size_t)(A_TOT / 32) * E_TOT * FEAT) * 4;
  if (ws_size >= needA) {
    constexpr int GE = E_TOT / 32, GA = A_TOT / 32;  // 64, 16
    float* ws_elec = ws_atom + (size_t)GE * A_TOT * FEAT;
    main_pass<32, 32><<<GE * GA, 256, 0, stream>>>(h, r_im, mu, sigma, ws_atom, ws_elec);
    finals<<<finals_grid, 256, 0, stream>>>(ws_atom, ws_elec, W, b, out, GE, GA);
  } else {
    // fallback: EB=64, AB=64 -> grid 256, slices = 8, ws = 16.8 MB
    constexpr int GE = E_TOT / 64, GA = A_TOT / 64;  // 32, 8
    float* ws_elec = ws_atom + (size_t)GE * A_TOT * FEAT;
    main_pass<64, 64><<<GE * GA, 256, 0, stream>>>(h, r_im, mu, sigma, ws_atom, ws_elec);
    finals<<<finals_grid, 256, 0, stream>>>(ws_atom, ws_elec, W, b, out, GE, GA);
  }
}

// Round 7
// 136.285 us; speedup vs baseline: 1.3053x; 1.0017x over previous
//
#include <hip/hip_runtime.h>
#include <cstdint>
#include <cstddef>

#define E_TOT 2048
#define A_TOT 512
#define FEAT  128
#define N_UP  1024
#define K_RBF 32
#define DIM   256
#define N_XCD 8

typedef float vfloat4 __attribute__((ext_vector_type(4)));

// ---------------------------------------------------------------------------
// Main pass, barrier-free hot loop + XCD-chunked block swizzle. Block owns
// (EB e x AB a). Default dispatch round-robins consecutive bids across the 8
// XCDs, shattering the h read into ~2k fine-grained streams. The swizzle
// wgid = (bid%8)*(nwg/8) + bid/8 gives each XCD a CONTIGUOUS run of logical
// blocks, so each XCD's 32 CUs sweep one dense region (same-g_e blocks land
// on one XCD and their 16KB chunks merge in that XCD's L2).
// ---------------------------------------------------------------------------
template <int EB, int AB>
__global__ __launch_bounds__(256) void main_pass(
    const float* __restrict__ h, const float* __restrict__ r_im,
    const float* __restrict__ mu, const float* __restrict__ sigma,
    float* __restrict__ ws_atom,   // [E_TOT/EB][A_TOT][FEAT]
    float* __restrict__ ws_elec) { // [GA][E_TOT][FEAT]
  constexpr int GA = A_TOT / AB;
  constexpr int WA = AB / 4;   // atoms per wave
  constexpr int NIA = AB / 8;  // 2 atoms per ia step
  static_assert(EB % 2 == 0, "EB even");
  // XCD-chunked bijective swizzle (gridDim.x % 8 == 0 by construction)
  const int nwg = gridDim.x;
  const int bid_raw = blockIdx.x;
  const int wgid = (bid_raw % N_XCD) * (nwg / N_XCD) + bid_raw / N_XCD;
  const int g_a = wgid % GA, g_e = wgid / GA;
  const int e0 = g_e * EB, a0 = g_a * AB;
  const int t = threadIdx.x;
  const int wave = t >> 6, lane = t & 63;
  const int f4 = lane & 31, r_lo = lane >> 5;

  __shared__ float s_mu[K_RBF], s_inv[K_RBF];
  __shared__ float rbf_lds[EB * AB];
  __shared__ float esum_lds[EB * FEAT];  // combined elec partial, 16 KB @EB=32

  if (t < K_RBF) {
    s_mu[t] = mu[t];
    float s = sigma[t];
    float sp = (s > 20.0f) ? s : log1pf(__expf(s));  // softplus
    s_inv[t] = 1.0f / sp;
  }
  __syncthreads();

  for (int i = t; i < EB * FEAT; i += 256) esum_lds[i] = 0.0f;
  for (int i = t; i < EB * AB; i += 256) {
    int e_l = i / AB, a_l = i % AB;
    float rv = r_im[(size_t)(e0 + e_l) * A_TOT + a0 + a_l];
    float acc = 0.0f;
#pragma unroll
    for (int k = 0; k < K_RBF; ++k) {
      float d = rv - s_mu[k];
      acc += __expf(-d * d * s_inv[k]);
    }
    rbf_lds[i] = acc * (1.0f / K_RBF);
  }
  __syncthreads();  // hot loop below is barrier-free

  vfloat4 acc[NIA];
#pragma unroll
  for (int i = 0; i < NIA; ++i) acc[i] = (vfloat4)(0.f);

  const float* hbase = h + ((size_t)e0 * A_TOT + a0) * FEAT;
  const int col = wave * WA + r_lo;  // atom offset for ia=0

  auto ldrow = [&](vfloat4* buf, int e) {
#pragma unroll
    for (int ia = 0; ia < NIA; ++ia) {
      const float* p = hbase + (size_t)e * (A_TOT * FEAT) +
                       (col + ia * 2) * FEAT + f4 * 4;
      buf[ia] = __builtin_nontemporal_load(reinterpret_cast<const vfloat4*>(p));
    }
  };
  auto process = [&](const vfloat4* buf, int e) {
    vfloat4 esum = (vfloat4)(0.f);
#pragma unroll
    for (int ia = 0; ia < NIA; ++ia) {
      float rb = rbf_lds[e * AB + col + ia * 2];
      vfloat4 v = buf[ia] * rb;
      acc[ia] += v;
      esum += v;
    }
    esum.x += __shfl_down(esum.x, 32, 64);
    esum.y += __shfl_down(esum.y, 32, 64);
    esum.z += __shfl_down(esum.z, 32, 64);
    esum.w += __shfl_down(esum.w, 32, 64);
    if (lane < 32) {
      float* p = &esum_lds[e * FEAT + f4 * 4];
      atomicAdd(p + 0, esum.x);
      atomicAdd(p + 1, esum.y);
      atomicAdd(p + 2, esum.z);
      atomicAdd(p + 3, esum.w);
    }
  };

  vfloat4 b0[NIA], b1[NIA];
  ldrow(b0, 0);
#pragma unroll 4
  for (int e = 0; e < EB; e += 2) {
    ldrow(b1, e + 1);
    process(b0, e);
    if (e + 2 < EB) ldrow(b0, e + 2);
    process(b1, e + 1);
  }

  // atom partials (no cross-wave dependence)
  vfloat4* ws_a4 = reinterpret_cast<vfloat4*>(ws_atom);
#pragma unroll
  for (int ia = 0; ia < NIA; ++ia) {
    const int a_l = col + ia * 2;
    ws_a4[((size_t)g_e * A_TOT + a0 + a_l) * 32 + f4] = acc[ia];
  }

  // combined elec slice write
  __syncthreads();
  vfloat4* ws_e4 = reinterpret_cast<vfloat4*>(ws_elec);
  const vfloat4* es4 = reinterpret_cast<const vfloat4*>(esum_lds);
#pragma unroll
  for (int i = t; i < EB * 32; i += 256) {
    const int e_l = i >> 5, ff = i & 31;
    ws_e4[((size_t)g_a * E_TOT + e0 + e_l) * 32 + ff] = es4[e_l * 32 + ff];
  }
}

// ---------------------------------------------------------------------------
// Merged epilogue. Blocks [0, A_TOT): one block per atom -> spin means,
// 256-dot, tanh*gain. Blocks [A_TOT, A_TOT+256): elec slice reduce.
// ---------------------------------------------------------------------------
__global__ __launch_bounds__(256) void finals(
    const float* __restrict__ ws_atom, const float* __restrict__ ws_elec,
    const float* __restrict__ W, const float* __restrict__ bias,
    float* __restrict__ out, int ge_total, int slices) {
  const int t = threadIdx.x;
  if (blockIdx.x < A_TOT) {
    const int a = blockIdx.x;
    __shared__ float s_in[2 * FEAT];
    const int spin = t >> 7;
    const int f = t & 127;
    const int gh = ge_total >> 1;
    const int g0 = spin * gh;
    float acc = 0.0f;
#pragma unroll 4
    for (int g = 0; g < gh; ++g) {
      acc += ws_atom[((size_t)(g0 + g) * A_TOT + a) * FEAT + f];
    }
    s_in[t] = acc * (1.0f / (float)N_UP);
    __syncthreads();
    float o = bias[t];
#pragma unroll 4
    for (int k = 0; k < 2 * FEAT; ++k) {
      o += s_in[k] * W[(size_t)k * DIM + t];
    }
    out[(size_t)a * DIM + t] = tanhf(o) * (5.0f / 3.0f);
  } else {
    const int idx = (int)(blockIdx.x - A_TOT) * 256 + t;  // vfloat4 index
    const int n4 = E_TOT * FEAT / 4;
    const vfloat4* in4 = reinterpret_cast<const vfloat4*>(ws_elec);
    vfloat4 s = (vfloat4)(0.f);
    for (int g = 0; g < slices; ++g) {
      s += in4[(size_t)g * n4 + idx];
    }
    s *= (1.0f / (float)A_TOT);
    reinterpret_cast<vfloat4*>(out + (size_t)A_TOT * DIM)[idx] = s;
  }
}

// ---------------------------------------------------------------------------
extern "C" void kernel_launch(void* const* d_in, const int* in_sizes, int n_in,
                              void* d_out, int out_size, void* d_ws, size_t ws_size,
                              hipStream_t stream) {
  const float* h     = (const float*)d_in[0];  // (2048,512,128)
  const float* r_im  = (const float*)d_in[1];  // (2048,512)
  const float* mu    = (const float*)d_in[2];  // (32,)
  const float* sigma = (const float*)d_in[3];  // (32,)
  const float* W     = (const float*)d_in[4];  // (256,256)
  const float* b     = (const float*)d_in[5];  // (256,)
  float* out = (float*)d_out;

  float* ws_atom = (float*)d_ws;
  const int finals_grid = A_TOT + (E_TOT * FEAT / 4) / 256;  // 512 + 256

  // preferred: EB=32, AB=32 -> grid 1024, slices = 16, ws = 33.5 MB
  const size_t needA = ((size_t)(E_TOT / 32) * A_TOT * FEAT +
                        (size_t)(A_TOT / 32) * E_TOT * FEAT) * 4;
  if (ws_size >= needA) {
    constexpr int GE = E_TOT / 32, GA = A_TOT / 32;  // 64, 16
    float* ws_elec = ws_atom + (size_t)GE * A_TOT * FEAT;
    main_pass<32, 32><<<GE * GA, 256, 0, stream>>>(h, r_im, mu, sigma, ws_atom, ws_elec);
    finals<<<finals_grid, 256, 0, stream>>>(ws_atom, ws_elec, W, b, out, GE, GA);
  } else {
    // fallback: EB=64, AB=64 -> grid 256, slices = 8, ws = 16.8 MB
    constexpr int GE = E_TOT / 64, GA = A_TOT / 64;  // 32, 8
    float* ws_elec = ws_atom + (size_t)GE * A_TOT * FEAT;
    main_pass<64, 64><<<GE * GA, 256, 0, stream>>>(h, r_im, mu, sigma, ws_atom, ws_elec);
    finals<<<finals_grid, 256, 0, stream>>>(ws_atom, ws_elec, W, b, out, GE, GA);
  }
}

// Round 8
// 129.349 us; speedup vs baseline: 1.3752x; 1.0536x over previous
//
#include <hip/hip_runtime.h>
#include <cstdint>
#include <cstddef>

#define E_TOT 2048
#define A_TOT 512
#define FEAT  128
#define N_UP  1024
#define K_RBF 32
#define DIM   256

typedef float vfloat4 __attribute__((ext_vector_type(4)));

// ---------------------------------------------------------------------------
// Main pass, long-burst variant. Block owns (EB e x AB=128 a), 4 waves.
// Wave w owns 32 consecutive atoms [w*32, w*32+32); lane: f4 = lane&31
// (float4 idx in FEAT), r_lo = lane>>5 pairs adjacent atoms. Per e the wave
// issues two 8-load chunks, each 8KB CONTIGUOUS (16 atoms x 512B), loads
// back-to-back -> long sequential DRAM bursts (vs 4KB groups before).
// Double-buffered per chunk slot; zero barriers in the hot loop.
// elec-partial: register esum over the full e-row, intra-wave shfl_down(32),
// LDS atomicAdd combine across waves; one slice per block (GA=4 slices).
// atom-partial: 16 float4 register accumulators, written at block end.
// ---------------------------------------------------------------------------
template <int EB>
__global__ __launch_bounds__(256) void main_pass(
    const float* __restrict__ h, const float* __restrict__ r_im,
    const float* __restrict__ mu, const float* __restrict__ sigma,
    float* __restrict__ ws_atom,   // [E_TOT/EB][A_TOT][FEAT]
    float* __restrict__ ws_elec) { // [GA][E_TOT][FEAT]
  constexpr int AB = 128;
  constexpr int GA = A_TOT / AB;  // 4
  const int bid = blockIdx.x;
  const int g_a = bid % GA, g_e = bid / GA;
  const int e0 = g_e * EB, a0 = g_a * AB;
  const int t = threadIdx.x;
  const int wave = t >> 6, lane = t & 63;
  const int f4 = lane & 31, r_lo = lane >> 5;

  __shared__ float s_mu[K_RBF], s_inv[K_RBF];
  __shared__ float rbf_lds[EB * AB];
  __shared__ float esum_lds[EB * FEAT];

  if (t < K_RBF) {
    s_mu[t] = mu[t];
    float s = sigma[t];
    float sp = (s > 20.0f) ? s : log1pf(__expf(s));  // softplus
    s_inv[t] = 1.0f / sp;
  }
  __syncthreads();

  for (int i = t; i < EB * FEAT; i += 256) esum_lds[i] = 0.0f;
  for (int i = t; i < EB * AB; i += 256) {
    int e_l = i / AB, a_l = i % AB;
    float rv = r_im[(size_t)(e0 + e_l) * A_TOT + a0 + a_l];
    float acc = 0.0f;
#pragma unroll
    for (int k = 0; k < K_RBF; ++k) {
      float d = rv - s_mu[k];
      acc += __expf(-d * d * s_inv[k]);
    }
    rbf_lds[i] = acc * (1.0f / K_RBF);
  }
  __syncthreads();  // hot loop below is barrier-free

  vfloat4 acc[16];
#pragma unroll
  for (int i = 0; i < 16; ++i) acc[i] = (vfloat4)(0.f);

  // per-lane base: atom wave*32 + r_lo, feature f4*4
  const float* hbase = h + ((size_t)e0 * A_TOT + a0) * FEAT +
                       (wave * 32 + r_lo) * FEAT + f4 * 4;
  const int arb = wave * 32 + r_lo;  // rbf atom base for this half-wave

  auto ldchunk = [&](vfloat4* buf, int e, int c) {
#pragma unroll
    for (int i = 0; i < 8; ++i) {
      const float* p = hbase + (size_t)e * (A_TOT * FEAT) +
                       (c * 8 + i) * (2 * FEAT);
      buf[i] = __builtin_nontemporal_load(reinterpret_cast<const vfloat4*>(p));
    }
  };

  vfloat4 esum;
  auto prchunk = [&](vfloat4* buf, int e, int c) {
#pragma unroll
    for (int i = 0; i < 8; ++i) {
      const int j = c * 8 + i;
      float rb = rbf_lds[e * AB + arb + j * 2];
      vfloat4 v = buf[i] * rb;
      acc[j] += v;
      esum += v;
    }
  };

  vfloat4 B0[8], B1[8];
  ldchunk(B0, 0, 0);
  ldchunk(B1, 0, 1);
  for (int e = 0; e < EB; ++e) {
    esum = (vfloat4)(0.f);
    prchunk(B0, e, 0);
    if (e + 1 < EB) ldchunk(B0, e + 1, 0);
    prchunk(B1, e, 1);
    if (e + 1 < EB) ldchunk(B1, e + 1, 1);
    // wave esum covers its 32 atoms; fold r_lo halves, combine across waves
    esum.x += __shfl_down(esum.x, 32, 64);
    esum.y += __shfl_down(esum.y, 32, 64);
    esum.z += __shfl_down(esum.z, 32, 64);
    esum.w += __shfl_down(esum.w, 32, 64);
    if (lane < 32) {
      float* p = &esum_lds[e * FEAT + f4 * 4];
      atomicAdd(p + 0, esum.x);
      atomicAdd(p + 1, esum.y);
      atomicAdd(p + 2, esum.z);
      atomicAdd(p + 3, esum.w);
    }
  }

  // atom partials
  vfloat4* ws_a4 = reinterpret_cast<vfloat4*>(ws_atom);
#pragma unroll
  for (int j = 0; j < 16; ++j) {
    const int a_l = wave * 32 + j * 2 + r_lo;
    ws_a4[((size_t)g_e * A_TOT + a0 + a_l) * 32 + f4] = acc[j];
  }

  // combined elec slice write
  __syncthreads();
  vfloat4* ws_e4 = reinterpret_cast<vfloat4*>(ws_elec);
  const vfloat4* es4 = reinterpret_cast<const vfloat4*>(esum_lds);
  for (int i = t; i < EB * 32; i += 256) {
    const int e_l = i >> 5, ff = i & 31;
    ws_e4[((size_t)g_a * E_TOT + e0 + e_l) * 32 + ff] = es4[e_l * 32 + ff];
  }
}

// ---------------------------------------------------------------------------
// Merged epilogue. Blocks [0, A_TOT): one block per atom -> spin means,
// 256-dot, tanh*gain. Blocks [A_TOT, A_TOT+256): elec slice reduce.
// ---------------------------------------------------------------------------
__global__ __launch_bounds__(256) void finals(
    const float* __restrict__ ws_atom, const float* __restrict__ ws_elec,
    const float* __restrict__ W, const float* __restrict__ bias,
    float* __restrict__ out, int ge_total, int slices) {
  const int t = threadIdx.x;
  if (blockIdx.x < A_TOT) {
    const int a = blockIdx.x;
    __shared__ float s_in[2 * FEAT];
    const int spin = t >> 7;
    const int f = t & 127;
    const int gh = ge_total >> 1;
    const int g0 = spin * gh;
    float acc = 0.0f;
#pragma unroll 4
    for (int g = 0; g < gh; ++g) {
      acc += ws_atom[((size_t)(g0 + g) * A_TOT + a) * FEAT + f];
    }
    s_in[t] = acc * (1.0f / (float)N_UP);
    __syncthreads();
    float o = bias[t];
#pragma unroll 4
    for (int k = 0; k < 2 * FEAT; ++k) {
      o += s_in[k] * W[(size_t)k * DIM + t];
    }
    out[(size_t)a * DIM + t] = tanhf(o) * (5.0f / 3.0f);
  } else {
    const int idx = (int)(blockIdx.x - A_TOT) * 256 + t;  // vfloat4 index
    const int n4 = E_TOT * FEAT / 4;
    const vfloat4* in4 = reinterpret_cast<const vfloat4*>(ws_elec);
    vfloat4 s = (vfloat4)(0.f);
    for (int g = 0; g < slices; ++g) {
      s += in4[(size_t)g * n4 + idx];
    }
    s *= (1.0f / (float)A_TOT);
    reinterpret_cast<vfloat4*>(out + (size_t)A_TOT * DIM)[idx] = s;
  }
}

// ---------------------------------------------------------------------------
extern "C" void kernel_launch(void* const* d_in, const int* in_sizes, int n_in,
                              void* d_out, int out_size, void* d_ws, size_t ws_size,
                              hipStream_t stream) {
  const float* h     = (const float*)d_in[0];  // (2048,512,128)
  const float* r_im  = (const float*)d_in[1];  // (2048,512)
  const float* mu    = (const float*)d_in[2];  // (32,)
  const float* sigma = (const float*)d_in[3];  // (32,)
  const float* W     = (const float*)d_in[4];  // (256,256)
  const float* b     = (const float*)d_in[5];  // (256,)
  float* out = (float*)d_out;

  float* ws_atom = (float*)d_ws;
  const int finals_grid = A_TOT + (E_TOT * FEAT / 4) / 256;  // 512 + 256
  constexpr int GA = 4;  // AB = 128

  // preferred: EB=16 -> grid 512 (2 blocks/CU), ws = 37.7 MB
  const size_t need16 = ((size_t)(E_TOT / 16) * A_TOT * FEAT +
                         (size_t)GA * E_TOT * FEAT) * 4;
  if (ws_size >= need16) {
    constexpr int GE = E_TOT / 16;  // 128
    float* ws_elec = ws_atom + (size_t)GE * A_TOT * FEAT;
    main_pass<16><<<GE * GA, 256, 0, stream>>>(h, r_im, mu, sigma, ws_atom, ws_elec);
    finals<<<finals_grid, 256, 0, stream>>>(ws_atom, ws_elec, W, b, out, GE, GA);
  } else {
    // fallback: EB=32 -> grid 256, ws = 21 MB
    constexpr int GE = E_TOT / 32;  // 64
    float* ws_elec = ws_atom + (size_t)GE * A_TOT * FEAT;
    main_pass<32><<<GE * GA, 256, 0, stream>>>(h, r_im, mu, sigma, ws_atom, ws_elec);
    finals<<<finals_grid, 256, 0, stream>>>(ws_atom, ws_elec, W, b, out, GE, GA);
  }
}